// Round 8
// baseline (4441.816 us; speedup 1.0000x reference)
//
#include <hip/hip_runtime.h>
#include <math.h>

#define B_SZ 32
#define T_SZ 2048
#define DIN 256
#define DH 256
#define FOUR_D 1024

// scan decomposition: 8 WGs per batch, 256 threads each; WG owns 32 dims
#define NW 8
#define DPW 32
#define COLS 128       // preact cols per WG (4 gates x 32 dims)
#define KSEG 2         // 256 threads = 128 cols x 2 K-segments
#define KLEN 128       // K elements per segment -> 128 U regs/thread

__global__ void zero_ws(unsigned int* p, int n) {
    int i = blockIdx.x * blockDim.x + threadIdx.x;
    if (i < n) p[i] = 0u;
}

// px[r][f] = bias[f] + sum_k x_row(r)[k] * W[k][f];  r = tt*32 + b   (R4-proven)
__global__ __launch_bounds__(256) void px_gemm(
    const float* __restrict__ x, const float* __restrict__ W,
    const float* __restrict__ bias, float* __restrict__ px,
    int t0)
{
    __shared__ float xt[16][DIN];
    const int tid = threadIdx.x;
    const int rbase = blockIdx.x * 16;

    {
        int row = tid >> 4;
        int seg = (tid & 15) * 16;
        int r = rbase + row;
        int bb = r & 31;
        int tt = r >> 5;
        const float4* s4 = (const float4*)(x + ((size_t)bb * T_SZ + (size_t)(t0 + tt)) * DIN + seg);
        float4* dst = (float4*)&xt[row][seg];
        dst[0] = s4[0]; dst[1] = s4[1]; dst[2] = s4[2]; dst[3] = s4[3];
    }
    __syncthreads();

    const int j = tid * 4;
    float4 bv = *(const float4*)&bias[j];
    float acc[16][4];
#pragma unroll
    for (int r = 0; r < 16; ++r) {
        acc[r][0] = bv.x; acc[r][1] = bv.y; acc[r][2] = bv.z; acc[r][3] = bv.w;
    }

    for (int k = 0; k < DIN; k += 4) {
        float4 w0 = *(const float4*)&W[(size_t)(k + 0) * FOUR_D + j];
        float4 w1 = *(const float4*)&W[(size_t)(k + 1) * FOUR_D + j];
        float4 w2 = *(const float4*)&W[(size_t)(k + 2) * FOUR_D + j];
        float4 w3 = *(const float4*)&W[(size_t)(k + 3) * FOUR_D + j];
#pragma unroll
        for (int r = 0; r < 16; ++r) {
            float4 xv = *(const float4*)&xt[r][k];
            acc[r][0] += xv.x * w0.x + xv.y * w1.x + xv.z * w2.x + xv.w * w3.x;
            acc[r][1] += xv.x * w0.y + xv.y * w1.y + xv.z * w2.y + xv.w * w3.y;
            acc[r][2] += xv.x * w0.z + xv.y * w1.z + xv.z * w2.z + xv.w * w3.z;
            acc[r][3] += xv.x * w0.w + xv.y * w1.w + xv.z * w2.w + xv.w * w3.w;
        }
    }

#pragma unroll
    for (int r = 0; r < 16; ++r) {
        float4 st = make_float4(acc[r][0], acc[r][1], acc[r][2], acc[r][3]);
        *(float4*)&px[((size_t)(rbase + r)) * FOUR_D + j] = st;
    }
}

// Transposed scan, 256-thread edition: blockIdx = b*NW + w; WG (b,w) owns dims
// [32w, 32w+32) = preact cols {256g + 32w + j}. 128 U-weights per thread,
// asm-pinned, launch_bounds(256,1) -> VGPR cap 512, so they CAN and (per R2's
// 52-VGPR evidence at 256thr) WILL stay register-resident. h exchange: proven
// R2 protocol — 64-bit agent-scope atomics, (tag<<32|bits), parity dbuf.
__global__ __launch_bounds__(256, 1) void lstm_scan6(
    const float* __restrict__ px, const float* __restrict__ U,
    float* __restrict__ out, unsigned long long* __restrict__ hbuf,
    float* __restrict__ cstate, int t0, int ct)
{
    __shared__ float h_lds[DH];
    __shared__ float red[KSEG][COLS + 4];
    __shared__ float act_s[COLS];

    const int b = blockIdx.x >> 3;     // batch (batch-contiguous)
    const int w = blockIdx.x & 7;      // WG-within-batch
    const int tid = threadIdx.x;
    const int c = tid & (COLS - 1);    // col within WG: 0..127
    const int seg = tid >> 7;          // 0..1
    const int kbase = seg << 7;        // 0 or 128
    const int gg = c >> 5, jj = c & 31;
    const int colg = (gg << 8) + (w << 5) + jj;   // global preact column

    // one-time: 128 U weights to registers, pinned against remat
    float ureg[KLEN];
#pragma unroll
    for (int kk = 0; kk < KLEN; ++kk) {
        ureg[kk] = U[(size_t)(kbase + kk) * FOUR_D + colg];
        asm volatile("" : "+v"(ureg[kk]));
    }

    float c_reg = 0.0f;
    if (tid < DPW) c_reg = cstate[b * DH + (w << 5) + tid];

    for (int tt = 0; tt < ct; ++tt) {
        const int s = t0 + tt + 1;     // computing h_s from h_{s-1}

        // px prefetch (independent of h): issue before the spin
        float pxv = 0.0f;
        if (tid < COLS)
            pxv = px[((size_t)tt * B_SZ + b) * FOUR_D + colg];

        // acquire h_{s-1}: each of the 256 threads polls exactly its own dim
        if (s == 1) {
            h_lds[tid] = 0.0f;
        } else {
            const unsigned long long want = (unsigned long long)(unsigned)(s - 1);
            const unsigned long long* slot = hbuf +
                (((size_t)((s - 1) & 1) * B_SZ + b) * DH + tid);
            unsigned long long v;
            do {
                v = __hip_atomic_load(slot, __ATOMIC_RELAXED,
                                      __HIP_MEMORY_SCOPE_AGENT);
            } while ((v >> 32) != want);
            h_lds[tid] = __uint_as_float((unsigned)v);
        }
        __syncthreads();   // B1: h_lds ready

        // U-GEMV critical path: 128 register FMAs, h broadcast from LDS
        float a0 = 0.f, a1 = 0.f, a2 = 0.f, a3 = 0.f;
#pragma unroll
        for (int i = 0; i < KLEN; i += 4) {
            float4 hv = *(const float4*)&h_lds[kbase + i];
            a0 += hv.x * ureg[i];     a1 += hv.y * ureg[i + 1];
            a2 += hv.z * ureg[i + 2]; a3 += hv.w * ureg[i + 3];
        }
        red[seg][c] = (a0 + a1) + (a2 + a3);
        __syncthreads();   // B2: partials ready

        if (tid < COLS) {
            float pre = pxv + red[0][tid] + red[1][tid];
            float a;
            if (tid < 96) {
                a = 1.0f / (1.0f + __expf(-pre));          // i, f, o
            } else {
                float e = __expf(-2.0f * pre);             // g = tanh
                a = 2.0f / (1.0f + e) - 1.0f;
            }
            act_s[tid] = a;
        }
        __syncthreads();   // B3: activations ready

        if (tid < DPW) {
            float ig = act_s[tid];
            float fg = act_s[32 + tid];
            float og = act_s[64 + tid];
            float gv = act_s[96 + tid];
            float cn = fg * c_reg + ig * gv;
            c_reg = cn;
            float ec = __expf(-2.0f * cn);
            float hn = og * (2.0f / (1.0f + ec) - 1.0f);
            const int d = (w << 5) + tid;
            // publish FIRST (critical path), out-store after
            unsigned long long pv =
                ((unsigned long long)(unsigned)s << 32) |
                (unsigned long long)__float_as_uint(hn);
            __hip_atomic_store(hbuf + (((size_t)(s & 1) * B_SZ + b) * DH + d),
                               pv, __ATOMIC_RELAXED, __HIP_MEMORY_SCOPE_AGENT);
            out[((size_t)b * T_SZ + (size_t)(s - 1)) * DH + d] = hn;
        }
        // no trailing barrier: next-iter h_lds writes happen only after B3_tt
        // (all threads), and all h_lds readers finished before B2_tt; red
        // rewrite gated behind B1_{tt+1}; act_s rewrite behind B2_{tt+1}.
    }

    if (tid < DPW) cstate[b * DH + (w << 5) + tid] = c_reg;
}

extern "C" void kernel_launch(void* const* d_in, const int* in_sizes, int n_in,
                              void* d_out, int out_size, void* d_ws, size_t ws_size,
                              hipStream_t stream) {
    const float* x    = (const float*)d_in[0];
    const float* W    = (const float*)d_in[1];
    const float* U    = (const float*)d_in[2];
    const float* bias = (const float*)d_in[3];
    float* out = (float*)d_out;

    // ws layout: cstate 32KB @0 | hbuf 128KB @32K | pxbuf @160K
    float* cstate = (float*)d_ws;
    unsigned long long* hbuf = (unsigned long long*)((char*)d_ws + 32 * 1024);
    size_t px_off = 160 * 1024;
    float* pxbuf = (float*)((char*)d_ws + px_off);

    size_t avail = (ws_size > px_off) ? (ws_size - px_off) : 0;
    size_t per_step = (size_t)B_SZ * FOUR_D * sizeof(float);  // 128 KB
    long ct_max = (long)(avail / per_step);
    int CT = (ct_max >= T_SZ) ? T_SZ : (int)ct_max;
    if (CT < 1) CT = 1;

    // zero cstate + hbuf each launch
    int zero_words = (160 * 1024) / 4;
    zero_ws<<<(zero_words + 255) / 256, 256, 0, stream>>>((unsigned int*)d_ws, zero_words);

    for (int t0 = 0; t0 < T_SZ; t0 += CT) {
        int ct = (T_SZ - t0 < CT) ? (T_SZ - t0) : CT;
        int rows = ct * B_SZ;
        px_gemm<<<rows / 16, 256, 0, stream>>>(x, W, bias, pxbuf, t0);
        lstm_scan6<<<B_SZ * NW, 256, 0, stream>>>(pxbuf, U, out, hbuf, cstate, t0, ct);
    }
}

// Round 9
// 3901.680 us; speedup vs baseline: 1.1384x; 1.1384x over previous
//
#include <hip/hip_runtime.h>
#include <math.h>

#define B_SZ 32
#define T_SZ 2048
#define DIN 256
#define DH 256
#define FOUR_D 1024

// scan decomposition: 8 WGs per batch, 512 threads each (R4-proven best)
#define NW 8
#define DPW 32
#define COLS 128       // preact cols per WG (4 gates x 32 dims)
#define KSEG 4         // 512 threads = 128 cols x 4 K-segments
#define KLEN 64        // K elements per segment -> 16 named float4 weights

__global__ void zero_ws(unsigned int* p, int n) {
    int i = blockIdx.x * blockDim.x + threadIdx.x;
    if (i < n) p[i] = 0u;
}

// px[r][f] = bias[f] + sum_k x_row(r)[k] * W[k][f];  r = tt*32 + b   (proven)
__global__ __launch_bounds__(256) void px_gemm(
    const float* __restrict__ x, const float* __restrict__ W,
    const float* __restrict__ bias, float* __restrict__ px,
    int t0)
{
    __shared__ float xt[16][DIN];
    const int tid = threadIdx.x;
    const int rbase = blockIdx.x * 16;

    {
        int row = tid >> 4;
        int seg = (tid & 15) * 16;
        int r = rbase + row;
        int bb = r & 31;
        int tt = r >> 5;
        const float4* s4 = (const float4*)(x + ((size_t)bb * T_SZ + (size_t)(t0 + tt)) * DIN + seg);
        float4* dst = (float4*)&xt[row][seg];
        dst[0] = s4[0]; dst[1] = s4[1]; dst[2] = s4[2]; dst[3] = s4[3];
    }
    __syncthreads();

    const int j = tid * 4;
    float4 bv = *(const float4*)&bias[j];
    float acc[16][4];
#pragma unroll
    for (int r = 0; r < 16; ++r) {
        acc[r][0] = bv.x; acc[r][1] = bv.y; acc[r][2] = bv.z; acc[r][3] = bv.w;
    }

    for (int k = 0; k < DIN; k += 4) {
        float4 w0 = *(const float4*)&W[(size_t)(k + 0) * FOUR_D + j];
        float4 w1 = *(const float4*)&W[(size_t)(k + 1) * FOUR_D + j];
        float4 w2 = *(const float4*)&W[(size_t)(k + 2) * FOUR_D + j];
        float4 w3 = *(const float4*)&W[(size_t)(k + 3) * FOUR_D + j];
#pragma unroll
        for (int r = 0; r < 16; ++r) {
            float4 xv = *(const float4*)&xt[r][k];
            acc[r][0] += xv.x * w0.x + xv.y * w1.x + xv.z * w2.x + xv.w * w3.x;
            acc[r][1] += xv.x * w0.y + xv.y * w1.y + xv.z * w2.y + xv.w * w3.y;
            acc[r][2] += xv.x * w0.z + xv.y * w1.z + xv.z * w2.z + xv.w * w3.z;
            acc[r][3] += xv.x * w0.w + xv.y * w1.w + xv.z * w2.w + xv.w * w3.w;
        }
    }

#pragma unroll
    for (int r = 0; r < 16; ++r) {
        float4 st = make_float4(acc[r][0], acc[r][1], acc[r][2], acc[r][3]);
        *(float4*)&px[((size_t)(rbase + r)) * FOUR_D + j] = st;
    }
}

// 16 named float4 weight registers: no array, no runtime indexing, no scratch
// path. Every access is a named member at a compile-time position.
#define REP16(M) M(0) M(1) M(2) M(3) M(4) M(5) M(6) M(7) \
                 M(8) M(9) M(10) M(11) M(12) M(13) M(14) M(15)

#define U_DECL(n) float4 u##n;
#define U_LOAD(n) u##n = make_float4(                         \
    Ucol[(size_t)(kbase + 4*(n) + 0) * FOUR_D],               \
    Ucol[(size_t)(kbase + 4*(n) + 1) * FOUR_D],               \
    Ucol[(size_t)(kbase + 4*(n) + 2) * FOUR_D],               \
    Ucol[(size_t)(kbase + 4*(n) + 3) * FOUR_D]);
#define GEMV_STEP(n) {                                        \
    float4 hv = *(const float4*)&h_lds[kbase + 4*(n)];        \
    a0 += hv.x * u##n.x; a1 += hv.y * u##n.y;                 \
    a2 += hv.z * u##n.z; a3 += hv.w * u##n.w; }

// Transposed scan (R4 structure): blockIdx = b*NW + w; WG (b,w) owns dims
// [32w,32w+32) = preact cols {256g+32w+j}. h exchange: proven agent-scope
// 64-bit tagged atomics, parity double-buffered.
__global__ __launch_bounds__(512, 2) void lstm_scan7(
    const float* __restrict__ px, const float* __restrict__ U,
    float* __restrict__ out, unsigned long long* __restrict__ hbuf,
    float* __restrict__ cstate, int t0, int ct)
{
    __shared__ float h_lds[DH];
    __shared__ float red[KSEG][COLS + 1];
    __shared__ float act_s[COLS];

    const int b = blockIdx.x >> 3;     // batch (batch-contiguous)
    const int w = blockIdx.x & 7;      // WG-within-batch
    const int tid = threadIdx.x;
    const int c = tid & (COLS - 1);    // col within WG: 0..127
    const int seg = tid >> 7;          // 0..3
    const int kbase = seg << 6;        // 0,64,128,192
    const int gg = c >> 5, jj = c & 31;
    const int colg = (gg << 8) + (w << 5) + jj;   // global preact column

    // one-time: 64 U weights into 16 NAMED float4 registers
    const float* Ucol = U + colg;
    REP16(U_DECL)
    REP16(U_LOAD)

    float c_reg = 0.0f;
    if (tid < DPW) c_reg = cstate[b * DH + (w << 5) + tid];

    for (int tt = 0; tt < ct; ++tt) {
        const int s = t0 + tt + 1;     // computing h_s from h_{s-1}

        // px prefetch (independent of h): issue before the spin
        float pxv = 0.0f;
        if (tid < COLS)
            pxv = px[((size_t)tt * B_SZ + b) * FOUR_D + colg];

        // acquire h_{s-1}: threads 0..255 poll their own dim (tag==step)
        if (tid < DH) {
            if (s == 1) {
                h_lds[tid] = 0.0f;
            } else {
                const unsigned long long want = (unsigned long long)(unsigned)(s - 1);
                const unsigned long long* slot = hbuf +
                    (((size_t)((s - 1) & 1) * B_SZ + b) * DH + tid);
                unsigned long long v;
                do {
                    v = __hip_atomic_load(slot, __ATOMIC_RELAXED,
                                          __HIP_MEMORY_SCOPE_AGENT);
                } while ((v >> 32) != want);
                h_lds[tid] = __uint_as_float((unsigned)v);
            }
        }
        __syncthreads();   // B1: h_lds ready

        // GEMV critical path: 64 FMAs from NAMED registers, h from LDS
        float a0 = 0.f, a1 = 0.f, a2 = 0.f, a3 = 0.f;
        REP16(GEMV_STEP)
        red[seg][c] = (a0 + a1) + (a2 + a3);
        __syncthreads();   // B2: partials ready

        if (tid < COLS) {
            float pre = pxv + red[0][tid] + red[1][tid]
                            + red[2][tid] + red[3][tid];
            float a;
            if (tid < 96) {
                a = 1.0f / (1.0f + __expf(-pre));          // i, f, o
            } else {
                float e = __expf(-2.0f * pre);             // g = tanh
                a = 2.0f / (1.0f + e) - 1.0f;
            }
            act_s[tid] = a;
        }
        __syncthreads();   // B3: activations ready

        if (tid < DPW) {
            float ig = act_s[tid];
            float fg = act_s[32 + tid];
            float og = act_s[64 + tid];
            float gv = act_s[96 + tid];
            float cn = fg * c_reg + ig * gv;
            c_reg = cn;
            float ec = __expf(-2.0f * cn);
            float hn = og * (2.0f / (1.0f + ec) - 1.0f);
            const int d = (w << 5) + tid;
            // publish FIRST (critical path), out-store after
            unsigned long long pv =
                ((unsigned long long)(unsigned)s << 32) |
                (unsigned long long)__float_as_uint(hn);
            __hip_atomic_store(hbuf + (((size_t)(s & 1) * B_SZ + b) * DH + d),
                               pv, __ATOMIC_RELAXED, __HIP_MEMORY_SCOPE_AGENT);
            out[((size_t)b * T_SZ + (size_t)(s - 1)) * DH + d] = hn;
        }
        // no trailing barrier: next-iter writers are gated behind next-iter
        // B1/B2/B3 rendezvous (same argument as R4).
    }

    if (tid < DPW) cstate[b * DH + (w << 5) + tid] = c_reg;
}

extern "C" void kernel_launch(void* const* d_in, const int* in_sizes, int n_in,
                              void* d_out, int out_size, void* d_ws, size_t ws_size,
                              hipStream_t stream) {
    const float* x    = (const float*)d_in[0];
    const float* W    = (const float*)d_in[1];
    const float* U    = (const float*)d_in[2];
    const float* bias = (const float*)d_in[3];
    float* out = (float*)d_out;

    // ws layout: cstate 32KB @0 | hbuf 128KB @32K | pxbuf @160K
    float* cstate = (float*)d_ws;
    unsigned long long* hbuf = (unsigned long long*)((char*)d_ws + 32 * 1024);
    size_t px_off = 160 * 1024;
    float* pxbuf = (float*)((char*)d_ws + px_off);

    size_t avail = (ws_size > px_off) ? (ws_size - px_off) : 0;
    size_t per_step = (size_t)B_SZ * FOUR_D * sizeof(float);  // 128 KB
    long ct_max = (long)(avail / per_step);
    int CT = (ct_max >= T_SZ) ? T_SZ : (int)ct_max;
    if (CT < 1) CT = 1;

    // zero cstate + hbuf each launch
    int zero_words = (160 * 1024) / 4;
    zero_ws<<<(zero_words + 255) / 256, 256, 0, stream>>>((unsigned int*)d_ws, zero_words);

    for (int t0 = 0; t0 < T_SZ; t0 += CT) {
        int ct = (T_SZ - t0 < CT) ? (T_SZ - t0) : CT;
        int rows = ct * B_SZ;
        px_gemm<<<rows / 16, 256, 0, stream>>>(x, W, bias, pxbuf, t0);
        lstm_scan7<<<B_SZ * NW, 512, 0, stream>>>(pxbuf, U, out, hbuf, cstate, t0, ct);
    }
}